// Round 10
// baseline (159.668 us; speedup 1.0000x reference)
//
#include <hip/hip_runtime.h>

#define T_LEN 1024
#define NH 8
#define DH 64
#define CCH 512
#define LOG2E 1.44269504088896340736f

typedef _Float16 f16;
typedef _Float16 f16x8 __attribute__((ext_vector_type(8)));
typedef _Float16 f16x4 __attribute__((ext_vector_type(4)));
typedef float f32x4 __attribute__((ext_vector_type(4)));

// async global->LDS DMA, 16B per lane. LDS dest must equal wave-uniform base + lane*16.
__device__ __forceinline__ void dma16(const void* g, void* l)
{
    __builtin_amdgcn_global_load_lds((const __attribute__((address_space(1))) void*)g,
                                     (__attribute__((address_space(3))) void*)l, 16, 0, 0);
}

// ---------------------------------------------------------------------------
// prep: transpose+cvt x -> xT fp16 [b*t][c]. grid(16, 8, 3B), block 256.
// (W conversion removed — proj kernels read W fp32 directly.)
// ---------------------------------------------------------------------------
__global__ __launch_bounds__(256)
void prep_kernel(const float* __restrict__ x0, const float* __restrict__ x1,
                 const float* __restrict__ x2, f16* __restrict__ o0,
                 f16* __restrict__ o1, f16* __restrict__ o2, int B)
{
    const int z = blockIdx.z;
    const int t0 = blockIdx.x * 64, c0 = blockIdx.y * 64;
    const int which = z / B, b = z % B;
    const float* x = (which == 0) ? x0 : (which == 1) ? x1 : x2;
    f16* o = (which == 0) ? o0 : (which == 1) ? o1 : o2;

    __shared__ float L[64 * 68];
    const int cl = threadIdx.x & 63, g = threadIdx.x >> 6;
    const float* src = x + ((size_t)(b * CCH + c0 + cl)) * T_LEN + t0 + g * 16;
    #pragma unroll
    for (int j = 0; j < 4; ++j)
        *(float4*)&L[cl * 68 + g * 16 + 4 * j] = *(const float4*)&src[4 * j];
    __syncthreads();
    const int tl = threadIdx.x & 63, cg = (threadIdx.x >> 6) * 16;
    f16 h[16];
    #pragma unroll
    for (int j = 0; j < 16; ++j) h[j] = (f16)L[(cg + j) * 68 + tl];
    f16* dst = o + ((size_t)(b * T_LEN + t0 + tl)) * CCH + c0 + cg;
    *(f16x8*)&dst[0] = *(f16x8*)&h[0];
    *(f16x8*)&dst[8] = *(f16x8*)&h[8];
}

// ---------------------------------------------------------------------------
// W fp32 -> swizzled f16 LDS staging helper: 64 rows x 64 c chunk.
// row = tid>>2 (0..63), c = (tid&3)*16. Two f16x8 writes, group-XOR swizzle.
// ---------------------------------------------------------------------------
__device__ __forceinline__ void stage_w_fp32(const float* __restrict__ Wg,
                                             int c1, f16* __restrict__ dstbuf,
                                             int wrow, int wc)
{
    float4 a = *(const float4*)&Wg[c1 + 0];
    float4 b = *(const float4*)&Wg[c1 + 4];
    float4 c = *(const float4*)&Wg[c1 + 8];
    float4 d = *(const float4*)&Wg[c1 + 12];
    f16 hh[16] = {(f16)a.x, (f16)a.y, (f16)a.z, (f16)a.w,
                  (f16)b.x, (f16)b.y, (f16)b.z, (f16)b.w,
                  (f16)c.x, (f16)c.y, (f16)c.z, (f16)c.w,
                  (f16)d.x, (f16)d.y, (f16)d.z, (f16)d.w};
    const int cg0 = (wc >> 3);   // first 8-group index
    *(f16x8*)&dstbuf[wrow * 64 + ((cg0 ^ (wrow & 7)) << 3)]       = *(f16x8*)&hh[0];
    *(f16x8*)&dstbuf[wrow * 64 + (((cg0 + 1) ^ (wrow & 7)) << 3)] = *(f16x8*)&hh[8];
}

// ---------------------------------------------------------------------------
// Fused q/k/v projections: X A-frags via register dbuf (xT f16), W staged
// DIRECTLY from fp32 (dbuf LDS, cvt in staging). 128(t)x64(o), BK=64.
// grid(B*8, 8, 3), block 256.
// ---------------------------------------------------------------------------
__global__ __launch_bounds__(256)
void proj_qkv(const f16* __restrict__ xq, const f16* __restrict__ xk,
              const f16* __restrict__ xv, const float* __restrict__ wq,
              const float* __restrict__ wk, const float* __restrict__ wv,
              const float* __restrict__ bq, const float* __restrict__ bk,
              const float* __restrict__ bv, f16* __restrict__ qo,
              f16* __restrict__ ko, f16* __restrict__ vo)
{
    const int which = blockIdx.z;
    const f16* X = (which == 0) ? xq : (which == 1) ? xk : xv;
    const float* W = (which == 0) ? wq : (which == 1) ? wk : wv;
    const float* bias = (which == 0) ? bq : (which == 1) ? bk : bv;
    const float scale = (which == 0) ? 0.125f * LOG2E : 1.0f;

    const int r0 = blockIdx.x * 128;
    const int o0 = blockIdx.y * 64;
    const int tid = threadIdx.x;
    const int w = tid >> 6, lane = tid & 63;
    const int quad = lane >> 4, l15 = lane & 15;

    __shared__ __align__(16) f16 Ws[2][4096];

    const int wrow = tid >> 2;          // 0..63
    const int wc   = (tid & 3) * 16;
    const float* Wg = W + (size_t)(o0 + wrow) * CCH + wc;

    stage_w_fp32(Wg, 0, Ws[0], wrow, wc);

    const f16* xp = X + (size_t)(r0 + 32 * w + l15) * CCH + quad * 8;
    f16x8 xf[2][2];
    #pragma unroll
    for (int ks = 0; ks < 2; ++ks)
        #pragma unroll
        for (int im = 0; im < 2; ++im)
            xf[ks][im] = *(const f16x8*)&xp[(size_t)(16 * im) * CCH + ks * 32];

    f32x4 acc[8] = {};

    for (int kc = 0; kc < 8; ++kc) {
        __syncthreads();   // W staging (chunk kc) + X prefetch complete
        if (kc < 7)
            stage_w_fp32(Wg, (kc + 1) * 64, Ws[(kc + 1) & 1], wrow, wc);
        const int nk = ((kc + 1) & 7) * 64;
        f16x8 xn[2][2];
        #pragma unroll
        for (int ks = 0; ks < 2; ++ks)
            #pragma unroll
            for (int im = 0; im < 2; ++im)
                xn[ks][im] = *(const f16x8*)&xp[(size_t)(16 * im) * CCH + nk + ks * 32];

        const int cb = kc & 1;
        #pragma unroll
        for (int ks = 0; ks < 2; ++ks) {
            const int sl = ((ks * 4 + quad) ^ (l15 & 7)) << 3;
            f16x8 wf[4];
            #pragma unroll
            for (int cm = 0; cm < 4; ++cm)
                wf[cm] = *(const f16x8*)&Ws[cb][(16 * cm + l15) * 64 + sl];
            if (which < 2) {
                #pragma unroll
                for (int im = 0; im < 2; ++im)
                    #pragma unroll
                    for (int cm = 0; cm < 4; ++cm)
                        acc[im * 4 + cm] = __builtin_amdgcn_mfma_f32_16x16x32_f16(
                            xf[ks][im], wf[cm], acc[im * 4 + cm], 0, 0, 0);
            } else {
                #pragma unroll
                for (int cm = 0; cm < 4; ++cm)
                    #pragma unroll
                    for (int in = 0; in < 2; ++in)
                        acc[cm * 2 + in] = __builtin_amdgcn_mfma_f32_16x16x32_f16(
                            wf[cm], xf[ks][in], acc[cm * 2 + in], 0, 0, 0);
            }
        }
        #pragma unroll
        for (int ks = 0; ks < 2; ++ks)
            #pragma unroll
            for (int im = 0; im < 2; ++im)
                xf[ks][im] = xn[ks][im];
    }

    if (which < 2) {
        f16* out = (which == 0) ? qo : ko;
        float bl[4];
        #pragma unroll
        for (int cm = 0; cm < 4; ++cm) bl[cm] = bias[o0 + 16 * cm + l15];
        #pragma unroll
        for (int im = 0; im < 2; ++im)
            #pragma unroll
            for (int r = 0; r < 4; ++r) {
                size_t row = (size_t)(r0 + 32 * w + 16 * im + 4 * quad + r) * CCH;
                #pragma unroll
                for (int cm = 0; cm < 4; ++cm)
                    out[row + o0 + 16 * cm + l15] =
                        (f16)((acc[im * 4 + cm][r] + bl[cm]) * scale);
            }
    } else {
        const int bb = r0 >> 10, tb = r0 & 1023;
        #pragma unroll
        for (int cm = 0; cm < 4; ++cm) {
            float4 bv4 = *(const float4*)&bias[o0 + 16 * cm + 4 * quad];
            float bl[4] = {bv4.x, bv4.y, bv4.z, bv4.w};
            #pragma unroll
            for (int r = 0; r < 4; ++r) {
                size_t row = ((size_t)(bb * CCH + o0 + 16 * cm + 4 * quad + r)) * T_LEN;
                #pragma unroll
                for (int in = 0; in < 2; ++in)
                    vo[row + tb + 32 * w + 16 * in + l15] =
                        (f16)(acc[cm * 2 + in][r] + bl[r]);
            }
        }
    }
}

// ---------------------------------------------------------------------------
// MFMA flash attention v8 = R8's v6 (64 Q-rows, 256 thr, one barrier/iter,
// cross-barrier DMA prefetch, wave-private Ps) + f16 embedding tables:
// LDS 53.8 -> 51.5 KB => 3 blocks/CU instead of 2 (the occupancy cliff).
// grid(16, NH, B), block 256. Writes final normalized ctx f16 [b*t][c].
// ---------------------------------------------------------------------------
__global__ __launch_bounds__(256)
void attn_mfma(const f16* __restrict__ q, const f16* __restrict__ kk,
               const f16* __restrict__ v, const float* __restrict__ ekg,
               const float* __restrict__ evg, f16* __restrict__ ctx)
{
    const int t0 = blockIdx.x * 64, h = blockIdx.y, b = blockIdx.z;
    const int tid = threadIdx.x;
    const int w = tid >> 6, lane = tid & 63;
    const int quad = lane >> 4, l15 = lane & 15;

    __shared__ __align__(16) f16 Qs[4096], Ps[4096];
    __shared__ __align__(16) f16 Ks[2][4096], Vs[2][4096];
    __shared__ f16 eks[576], evs[576];
    __shared__ float ls[64];

    const int srow = tid >> 3;
    const int scol = ((tid & 7) ^ (srow & 7)) << 3;

    for (int i = tid; i < 576; i += 256) {
        eks[i] = (f16)ekg[h * 576 + i];
        evs[i] = (f16)evg[h * 576 + i];
    }

    const f16* gk = kk + ((size_t)(b * T_LEN + srow)) * CCH + h * DH + scol;
    const f16* gv = v + ((size_t)(b * CCH + h * DH + srow)) * T_LEN + scol;

    // prologue: Q + tile 0 into buf 0
    dma16(q + ((size_t)(b * T_LEN + t0 + srow)) * CCH + h * DH + scol, &Qs[(size_t)tid * 8]);
    dma16(q + ((size_t)(b * T_LEN + t0 + srow + 32)) * CCH + h * DH + scol, &Qs[((size_t)tid + 256) * 8]);
    dma16(gk, &Ks[0][(size_t)tid * 8]);
    dma16(gk + (size_t)32 * CCH, &Ks[0][((size_t)tid + 256) * 8]);
    dma16(gv, &Vs[0][(size_t)tid * 8]);
    dma16(gv + (size_t)32 * T_LEN, &Vs[0][((size_t)tid + 256) * 8]);
    __syncthreads();

    f16x8 qf[2];
    #pragma unroll
    for (int ks = 0; ks < 2; ++ks)
        qf[ks] = *(const f16x8*)&Qs[(16 * w + l15) * 64 + (((ks * 4 + quad) ^ (l15 & 7)) << 3)];

    const int myt = 16 * w + l15;
    float Ssum = 0.f;
    f32x4 O[4] = {};

    const bool corner_hi = (blockIdx.x == 0);
    const bool corner_lo = (blockIdx.x == 15);

    for (int it = 0; it < 16; ++it) {
        const int kb = it, cb = it & 1;
        if (it) __syncthreads();   // single barrier: drains DMA(tile it)

        // prefetch DMA for tile it+1 (flies across the whole iteration)
        if (it < 15) {
            const int nb = cb ^ 1;
            dma16(gk + (size_t)((it + 1) * 64) * CCH, &Ks[nb][(size_t)tid * 8]);
            dma16(gk + (size_t)((it + 1) * 64 + 32) * CCH, &Ks[nb][((size_t)tid + 256) * 8]);
            dma16(gv + (it + 1) * 64, &Vs[nb][(size_t)tid * 8]);
            dma16(gv + (size_t)32 * T_LEN + (it + 1) * 64, &Vs[nb][((size_t)tid + 256) * 8]);
        }

        // ----- S^T = K Q^T -----
        f32x4 S[4] = {};
        #pragma unroll
        for (int ks = 0; ks < 2; ++ks) {
            #pragma unroll
            for (int ct = 0; ct < 4; ++ct) {
                f16x8 a = *(const f16x8*)&Ks[cb][(16 * ct + l15) * 64 + (((ks * 4 + quad) ^ (l15 & 7)) << 3)];
                S[ct] = __builtin_amdgcn_mfma_f32_16x16x32_f16(a, qf[ks], S[ct], 0, 0, 0);
            }
        }

        // ----- corner relative-K bias (rare) -----
        if ((corner_hi && kb == 15) || (corner_lo && kb == 0)) {
            const int s0g = kb * 64;
            #pragma unroll
            for (int ct = 0; ct < 4; ++ct)
                #pragma unroll
                for (int r = 0; r < 4; ++r) {
                    int t_g = t0 + myt;
                    int s_g = s0g + 16 * ct + 4 * quad + r;
                    int df = s_g - t_g;
                    if (df >= 1019 && df <= 1023) {
                        const f16* ekp = &eks[(df - 1019) * 64];
                        float sacc = 0.f;
                        for (int d = 0; d < 64; ++d)
                            sacc += (float)Qs[myt * 64 + (((d >> 3) ^ (myt & 7)) << 3) + (d & 7)] * (float)ekp[d];
                        S[ct][r] += sacc;
                    } else if (df >= -1023 && df <= -1021) {
                        const f16* ekp = &eks[(1029 + df) * 64];
                        const int t2 = myt - 1;
                        float sacc = 0.f;
                        for (int d = 0; d < 64; ++d)
                            sacc += (float)Qs[t2 * 64 + (((d >> 3) ^ (t2 & 7)) << 3) + (d & 7)] * (float)ekp[d];
                        S[ct][r] += sacc;
                    }
                }
        }

        // ----- no-max softmax: P = exp2(S); store Ps (wave-private rows) -----
        #pragma unroll
        for (int ct = 0; ct < 4; ++ct) {
            f16x4 pk_;
            #pragma unroll
            for (int r = 0; r < 4; ++r) {
                float p = exp2f(S[ct][r]);
                Ssum += p;
                pk_[r] = (f16)p;
            }
            int colh = (((2 * ct + (quad >> 1)) ^ (myt & 7)) << 3) + (quad & 1) * 4;
            *(f16x4*)&Ps[myt * 64 + colh] = pk_;
        }
        // no barrier: Ps rows 16w..16w+15 written & read by wave w only.

        // ----- O += P V -----
        #pragma unroll
        for (int ks = 0; ks < 2; ++ks) {
            f16x8 a = *(const f16x8*)&Ps[(16 * w + l15) * 64 + (((ks * 4 + quad) ^ (l15 & 7)) << 3)];
            #pragma unroll
            for (int ct = 0; ct < 4; ++ct) {
                f16x8 bf = *(const f16x8*)&Vs[cb][(16 * ct + l15) * 64 + (((ks * 4 + quad) ^ (l15 & 7)) << 3)];
                O[ct] = __builtin_amdgcn_mfma_f32_16x16x32_f16(a, bf, O[ct], 0, 0, 0);
            }
        }

        // ----- windowed relative-V (reads own wave's Ps rows) -----
        const int s0g = kb * 64;
        if (s0g <= t0 + 67 && s0g + 63 >= t0 - 4) {
            #pragma unroll
            for (int r = 0; r < 4; ++r) {
                int t_loc = 16 * w + 4 * quad + r;
                int t_g = t0 + t_loc;
                int slo = max(s0g, t_g - 4), shi = min(s0g + 63, t_g + 4);
                for (int s = slo; s <= shi; ++s) {
                    int sl = s - s0g;
                    float p = (float)Ps[t_loc * 64 + (((sl >> 3) ^ (t_loc & 7)) << 3) + (sl & 7)];
                    const f16* evp = &evs[(s - t_g + 4) * 64];
                    #pragma unroll
                    for (int ct = 0; ct < 4; ++ct)
                        O[ct][r] += p * (float)evp[16 * ct + l15];
                }
            }
        }
    }

    // full row-sum -> normalize in-kernel
    Ssum += __shfl_xor(Ssum, 16);
    Ssum += __shfl_xor(Ssum, 32);
    if (quad == 0) ls[myt] = 1.0f / Ssum;
    __syncthreads();

    #pragma unroll
    for (int r = 0; r < 4; ++r) {
        const int t_loc = 16 * w + 4 * quad + r;
        const float rl = ls[t_loc];
        size_t rowo = ((size_t)(b * T_LEN + t0 + t_loc)) * CCH + h * DH;
        #pragma unroll
        for (int ct = 0; ct < 4; ++ct)
            ctx[rowo + 16 * ct + l15] = (f16)(O[ct][r] * rl);
    }
}

// ---------------------------------------------------------------------------
// Output projection: ctx B-frags via register dbuf, Wo staged DIRECTLY from
// fp32 (dbuf LDS). 64(o)x64(t), BK=64. grid(B*16, 8). fp32 out [b][o][t].
// ---------------------------------------------------------------------------
__global__ __launch_bounds__(256)
void proj_out(const f16* __restrict__ ctx, const float* __restrict__ Wo,
              const float* __restrict__ bo, float* __restrict__ out)
{
    const int r0 = blockIdx.x * 64;
    const int o0 = blockIdx.y * 64;
    const int tid = threadIdx.x;
    const int w = tid >> 6, lane = tid & 63;
    const int quad = lane >> 4, l15 = lane & 15;

    __shared__ __align__(16) f16 Ws[2][4096];

    const int wrow = tid >> 2;
    const int wc   = (tid & 3) * 16;
    const float* Wg = Wo + (size_t)(o0 + wrow) * CCH + wc;

    stage_w_fp32(Wg, 0, Ws[0], wrow, wc);

    const f16* cp = ctx + (size_t)(r0 + 16 * w + l15) * CCH + quad * 8;
    f16x8 cf[2];
    #pragma unroll
    for (int ks = 0; ks < 2; ++ks)
        cf[ks] = *(const f16x8*)&cp[ks * 32];

    f32x4 acc[4] = {};

    for (int kc = 0; kc < 8; ++kc) {
        __syncthreads();
        if (kc < 7)
            stage_w_fp32(Wg, (kc + 1) * 64, Ws[(kc + 1) & 1], wrow, wc);
        const int nk = ((kc + 1) & 7) * 64;
        f16x8 cn[2];
        #pragma unroll
        for (int ks = 0; ks < 2; ++ks)
            cn[ks] = *(const f16x8*)&cp[nk + ks * 32];

        const int cb = kc & 1;
        #pragma unroll
        for (int ks = 0; ks < 2; ++ks) {
            const int sl = ((ks * 4 + quad) ^ (l15 & 7)) << 3;
            #pragma unroll
            for (int cm = 0; cm < 4; ++cm) {
                f16x8 wf = *(const f16x8*)&Ws[cb][(16 * cm + l15) * 64 + sl];
                acc[cm] = __builtin_amdgcn_mfma_f32_16x16x32_f16(wf, cf[ks], acc[cm], 0, 0, 0);
            }
        }
        cf[0] = cn[0];
        cf[1] = cn[1];
    }

    const int bb = r0 >> 10, tb = r0 & 1023;
    #pragma unroll
    for (int cm = 0; cm < 4; ++cm) {
        float4 bv4 = *(const float4*)&bo[o0 + 16 * cm + 4 * quad];
        float bl[4] = {bv4.x, bv4.y, bv4.z, bv4.w};
        #pragma unroll
        for (int r = 0; r < 4; ++r) {
            size_t row = ((size_t)(bb * CCH + o0 + 16 * cm + 4 * quad + r)) * T_LEN;
            out[row + tb + 16 * w + l15] = acc[cm][r] + bl[r];
        }
    }
}

// ---------------------------------------------------------------------------
extern "C" void kernel_launch(void* const* d_in, const int* in_sizes, int n_in,
                              void* d_out, int out_size, void* d_ws, size_t ws_size,
                              hipStream_t stream)
{
    const float* x_q = (const float*)d_in[0];
    const float* x_k = (const float*)d_in[1];
    const float* x_v = (const float*)d_in[2];
    const float* Wq  = (const float*)d_in[3];
    const float* bq  = (const float*)d_in[4];
    const float* Wk  = (const float*)d_in[5];
    const float* bk  = (const float*)d_in[6];
    const float* Wv  = (const float*)d_in[7];
    const float* bv  = (const float*)d_in[8];
    const float* Wo  = (const float*)d_in[9];
    const float* bo  = (const float*)d_in[10];
    const float* erk = (const float*)d_in[11];
    const float* erv = (const float*)d_in[12];

    const int B = in_sizes[0] / (CCH * T_LEN);
    const size_t te = (size_t)B * CCH * T_LEN;

    f16* p = (f16*)d_ws;
    f16* xTq = p; p += te;
    f16* xTk = p; p += te;
    f16* xTv = p; p += te;
    f16* qh  = p; p += te;
    f16* kh  = p; p += te;
    f16* vh  = p; p += te;
    f16* ch  = p; p += te;

    dim3 blk(256);
    prep_kernel<<<dim3(16, 8, 3 * B), blk, 0, stream>>>(
        x_q, x_k, x_v, xTq, xTk, xTv, B);
    proj_qkv<<<dim3(B * 8, 8, 3), blk, 0, stream>>>(
        xTq, xTk, xTv, Wq, Wk, Wv, bq, bk, bv, qh, kh, vh);
    attn_mfma<<<dim3(T_LEN / 64, NH, B), blk, 0, stream>>>(
        qh, kh, vh, erk, erv, ch);
    proj_out<<<dim3(B * 16, 8), blk, 0, stream>>>(
        ch, Wo, bo, (float*)d_out);
}

// Round 11
// 152.085 us; speedup vs baseline: 1.0499x; 1.0499x over previous
//
#include <hip/hip_runtime.h>

#define T_LEN 1024
#define NH 8
#define DH 64
#define CCH 512
#define LOG2E 1.44269504088896340736f

typedef _Float16 f16;
typedef _Float16 f16x8 __attribute__((ext_vector_type(8)));
typedef _Float16 f16x4 __attribute__((ext_vector_type(4)));
typedef float f32x4 __attribute__((ext_vector_type(4)));

// async global->LDS DMA, 16B per lane. LDS dest must equal wave-uniform base + lane*16.
__device__ __forceinline__ void dma16(const void* g, void* l)
{
    __builtin_amdgcn_global_load_lds((const __attribute__((address_space(1))) void*)g,
                                     (__attribute__((address_space(3))) void*)l, 16, 0, 0);
}

// ---------------------------------------------------------------------------
// prep: fused [transpose+cvt x -> xT fp16 [b*t][c]] and [W fp32 -> fp16].
// grid(16, 8, 3B + 8), block 256. (R8 version)
// ---------------------------------------------------------------------------
__global__ __launch_bounds__(256)
void prep_kernel(const float* __restrict__ x0, const float* __restrict__ x1,
                 const float* __restrict__ x2, const float* __restrict__ W0,
                 const float* __restrict__ W1, const float* __restrict__ W2,
                 const float* __restrict__ W3, f16* __restrict__ o0,
                 f16* __restrict__ o1, f16* __restrict__ o2, f16* __restrict__ w0,
                 f16* __restrict__ w1, f16* __restrict__ w2, f16* __restrict__ w3,
                 int B)
{
    const int z = blockIdx.z;
    if (z < 3 * B) {
        const int t0 = blockIdx.x * 64, c0 = blockIdx.y * 64;
        const int which = z / B, b = z % B;
        const float* x = (which == 0) ? x0 : (which == 1) ? x1 : x2;
        f16* o = (which == 0) ? o0 : (which == 1) ? o1 : o2;

        __shared__ float L[64 * 68];
        const int cl = threadIdx.x & 63, g = threadIdx.x >> 6;
        const float* src = x + ((size_t)(b * CCH + c0 + cl)) * T_LEN + t0 + g * 16;
        #pragma unroll
        for (int j = 0; j < 4; ++j)
            *(float4*)&L[cl * 68 + g * 16 + 4 * j] = *(const float4*)&src[4 * j];
        __syncthreads();
        const int tl = threadIdx.x & 63, cg = (threadIdx.x >> 6) * 16;
        f16 h[16];
        #pragma unroll
        for (int j = 0; j < 16; ++j) h[j] = (f16)L[(cg + j) * 68 + tl];
        f16* dst = o + ((size_t)(b * T_LEN + t0 + tl)) * CCH + c0 + cg;
        *(f16x8*)&dst[0] = *(f16x8*)&h[0];
        *(f16x8*)&dst[8] = *(f16x8*)&h[8];
    } else {
        const int slice = z - 3 * B;
        size_t i = ((size_t)(slice * 128 + blockIdx.y * 16 + blockIdx.x) * 256 + threadIdx.x) * 4;
        const int wi = (int)(i >> 18);
        const size_t off = i & 262143;
        const float* src = (wi == 0) ? W0 : (wi == 1) ? W1 : (wi == 2) ? W2 : W3;
        f16* dst = (wi == 0) ? w0 : (wi == 1) ? w1 : (wi == 2) ? w2 : w3;
        float4 v4 = *(const float4*)&src[off];
        f16x4 h = {(f16)v4.x, (f16)v4.y, (f16)v4.z, (f16)v4.w};
        *(f16x4*)&dst[off] = h;
    }
}

// ---------------------------------------------------------------------------
// m97-style fused q/k/v projection: 128x128 tile, BK=64, SINGLE-buffered
// dma16 staging (2 barriers/chunk), XOR-swizzled LDS, 32 KB -> 4-5 blocks/CU.
// Wave w computes the 64x64 quadrant (row-half w>>1, col-half w&1): acc 4x4,
// 32 MFMA per chunk per wave. grid(B*T/128, 4, 3), block 256.
// which=0,1 (q,k): D[t][o] -> [b*t][c] f16 (q scaled); which=2 (v): D[o][t]
// -> [b][c][t] f16.
// ---------------------------------------------------------------------------
__global__ __launch_bounds__(256)
void proj_qkv(const f16* __restrict__ xq, const f16* __restrict__ xk,
              const f16* __restrict__ xv, const f16* __restrict__ wq,
              const f16* __restrict__ wk, const f16* __restrict__ wv,
              const float* __restrict__ bq, const float* __restrict__ bk,
              const float* __restrict__ bv, f16* __restrict__ qo,
              f16* __restrict__ ko, f16* __restrict__ vo)
{
    const int which = blockIdx.z;
    const f16* X = (which == 0) ? xq : (which == 1) ? xk : xv;
    const f16* W = (which == 0) ? wq : (which == 1) ? wk : wv;
    const float* bias = (which == 0) ? bq : (which == 1) ? bk : bv;
    const float scale = (which == 0) ? 0.125f * LOG2E : 1.0f;

    const int r0 = blockIdx.x * 128;   // flat (b,t)
    const int o0 = blockIdx.y * 128;   // out channel
    const int tid = threadIdx.x;
    const int w = tid >> 6, lane = tid & 63;
    const int quad = lane >> 4, l15 = lane & 15;
    const int a  = w >> 1;             // row-half of D
    const int b2 = w & 1;              // col-half of D

    __shared__ __align__(16) f16 Xs[128 * 64];
    __shared__ __align__(16) f16 Wsh[128 * 64];

    const int srow = tid >> 3;                       // 0..31 (+32j)
    const int scol = ((tid & 7) ^ (srow & 7)) << 3;

    const f16* Xg = X + (size_t)(r0 + srow) * CCH + scol;
    const f16* Wg = W + (size_t)(o0 + srow) * CCH + scol;

    const int ax = (which < 2) ? a : b2;   // Xs half used as rows/cols
    const int aw = (which < 2) ? b2 : a;   // Wsh half

    f32x4 acc[4][4] = {};

    for (int kc = 0; kc < 8; ++kc) {
        if (kc) __syncthreads();           // readers of previous chunk done
        const int c1 = kc * 64;
        #pragma unroll
        for (int jj = 0; jj < 4; ++jj) {
            dma16(Xg + c1 + (size_t)(32 * jj) * CCH, &Xs[((size_t)tid + 256 * jj) * 8]);
            dma16(Wg + c1 + (size_t)(32 * jj) * CCH, &Wsh[((size_t)tid + 256 * jj) * 8]);
        }
        __syncthreads();                   // drain DMA

        #pragma unroll
        for (int ks = 0; ks < 2; ++ks) {
            const int sl = ((ks * 4 + quad) ^ (l15 & 7)) << 3;
            f16x8 xf[4], wf[4];
            #pragma unroll
            for (int i = 0; i < 4; ++i)
                xf[i] = *(const f16x8*)&Xs[(64 * ax + 16 * i + l15) * 64 + sl];
            #pragma unroll
            for (int j = 0; j < 4; ++j)
                wf[j] = *(const f16x8*)&Wsh[(64 * aw + 16 * j + l15) * 64 + sl];
            if (which < 2) {
                #pragma unroll
                for (int i = 0; i < 4; ++i)
                    #pragma unroll
                    for (int j = 0; j < 4; ++j)
                        acc[i][j] = __builtin_amdgcn_mfma_f32_16x16x32_f16(
                            xf[i], wf[j], acc[i][j], 0, 0, 0);
            } else {
                #pragma unroll
                for (int i = 0; i < 4; ++i)
                    #pragma unroll
                    for (int j = 0; j < 4; ++j)
                        acc[i][j] = __builtin_amdgcn_mfma_f32_16x16x32_f16(
                            wf[i], xf[j], acc[i][j], 0, 0, 0);
            }
        }
    }

    if (which < 2) {
        // D[t][o]: rows t = r0+64a+16i+4quad+r, cols o = o0+64b2+16j+l15
        f16* out = (which == 0) ? qo : ko;
        float bl[4];
        #pragma unroll
        for (int j = 0; j < 4; ++j) bl[j] = bias[o0 + 64 * b2 + 16 * j + l15];
        #pragma unroll
        for (int i = 0; i < 4; ++i)
            #pragma unroll
            for (int r = 0; r < 4; ++r) {
                size_t row = (size_t)(r0 + 64 * a + 16 * i + 4 * quad + r) * CCH;
                #pragma unroll
                for (int j = 0; j < 4; ++j)
                    out[row + o0 + 64 * b2 + 16 * j + l15] =
                        (f16)((acc[i][j][r] + bl[j]) * scale);
            }
    } else {
        // D[o][t]: rows o = o0+64a+16i+4quad+r, cols t = 64b2+16j+l15
        const int bb = r0 >> 10, tb = r0 & 1023;
        #pragma unroll
        for (int i = 0; i < 4; ++i) {
            float4 bv4 = *(const float4*)&bias[o0 + 64 * a + 16 * i + 4 * quad];
            float bl[4] = {bv4.x, bv4.y, bv4.z, bv4.w};
            #pragma unroll
            for (int r = 0; r < 4; ++r) {
                size_t row = ((size_t)(bb * CCH + o0 + 64 * a + 16 * i + 4 * quad + r)) * T_LEN;
                #pragma unroll
                for (int j = 0; j < 4; ++j)
                    vo[row + tb + 64 * b2 + 16 * j + l15] =
                        (f16)(acc[i][j][r] + bl[r]);
            }
        }
    }
}

// ---------------------------------------------------------------------------
// MFMA flash attention (exact R8 v6): 64 Q-rows/block, 256 thr, one barrier
// per K-iter, cross-barrier dma16 prefetch (dbuf K/V), wave-private Ps,
// no-max softmax, in-kernel normalization. 52.75 KB LDS -> 3 blocks/CU.
// grid(16, NH, B), block 256. Writes final normalized ctx f16 [b*t][c].
// ---------------------------------------------------------------------------
__global__ __launch_bounds__(256)
void attn_mfma(const f16* __restrict__ q, const f16* __restrict__ kk,
               const f16* __restrict__ v, const float* __restrict__ ekg,
               const float* __restrict__ evg, f16* __restrict__ ctx)
{
    const int t0 = blockIdx.x * 64, h = blockIdx.y, b = blockIdx.z;
    const int tid = threadIdx.x;
    const int w = tid >> 6, lane = tid & 63;
    const int quad = lane >> 4, l15 = lane & 15;

    __shared__ __align__(16) f16 Qs[4096], Ps[4096];
    __shared__ __align__(16) f16 Ks[2][4096], Vs[2][4096];
    __shared__ float eks[576], evs[576];
    __shared__ float ls[64];

    const int srow = tid >> 3;
    const int scol = ((tid & 7) ^ (srow & 7)) << 3;

    for (int i = tid; i < 576; i += 256) {
        eks[i] = ekg[h * 576 + i];
        evs[i] = evg[h * 576 + i];
    }

    const f16* gk = kk + ((size_t)(b * T_LEN + srow)) * CCH + h * DH + scol;
    const f16* gv = v + ((size_t)(b * CCH + h * DH + srow)) * T_LEN + scol;

    dma16(q + ((size_t)(b * T_LEN + t0 + srow)) * CCH + h * DH + scol, &Qs[(size_t)tid * 8]);
    dma16(q + ((size_t)(b * T_LEN + t0 + srow + 32)) * CCH + h * DH + scol, &Qs[((size_t)tid + 256) * 8]);
    dma16(gk, &Ks[0][(size_t)tid * 8]);
    dma16(gk + (size_t)32 * CCH, &Ks[0][((size_t)tid + 256) * 8]);
    dma16(gv, &Vs[0][(size_t)tid * 8]);
    dma16(gv + (size_t)32 * T_LEN, &Vs[0][((size_t)tid + 256) * 8]);
    __syncthreads();

    f16x8 qf[2];
    #pragma unroll
    for (int ks = 0; ks < 2; ++ks)
        qf[ks] = *(const f16x8*)&Qs[(16 * w + l15) * 64 + (((ks * 4 + quad) ^ (l15 & 7)) << 3)];

    const int myt = 16 * w + l15;
    float Ssum = 0.f;
    f32x4 O[4] = {};

    const bool corner_hi = (blockIdx.x == 0);
    const bool corner_lo = (blockIdx.x == 15);

    for (int it = 0; it < 16; ++it) {
        const int kb = it, cb = it & 1;
        if (it) __syncthreads();

        if (it < 15) {
            const int nb = cb ^ 1;
            dma16(gk + (size_t)((it + 1) * 64) * CCH, &Ks[nb][(size_t)tid * 8]);
            dma16(gk + (size_t)((it + 1) * 64 + 32) * CCH, &Ks[nb][((size_t)tid + 256) * 8]);
            dma16(gv + (it + 1) * 64, &Vs[nb][(size_t)tid * 8]);
            dma16(gv + (size_t)32 * T_LEN + (it + 1) * 64, &Vs[nb][((size_t)tid + 256) * 8]);
        }

        f32x4 S[4] = {};
        #pragma unroll
        for (int ks = 0; ks < 2; ++ks) {
            #pragma unroll
            for (int ct = 0; ct < 4; ++ct) {
                f16x8 aa = *(const f16x8*)&Ks[cb][(16 * ct + l15) * 64 + (((ks * 4 + quad) ^ (l15 & 7)) << 3)];
                S[ct] = __builtin_amdgcn_mfma_f32_16x16x32_f16(aa, qf[ks], S[ct], 0, 0, 0);
            }
        }

        if ((corner_hi && kb == 15) || (corner_lo && kb == 0)) {
            const int s0g = kb * 64;
            #pragma unroll
            for (int ct = 0; ct < 4; ++ct)
                #pragma unroll
                for (int r = 0; r < 4; ++r) {
                    int t_g = t0 + myt;
                    int s_g = s0g + 16 * ct + 4 * quad + r;
                    int df = s_g - t_g;
                    if (df >= 1019 && df <= 1023) {
                        const float* ekp = &eks[(df - 1019) * 64];
                        float sacc = 0.f;
                        for (int d = 0; d < 64; ++d)
                            sacc += (float)Qs[myt * 64 + (((d >> 3) ^ (myt & 7)) << 3) + (d & 7)] * ekp[d];
                        S[ct][r] += sacc;
                    } else if (df >= -1023 && df <= -1021) {
                        const float* ekp = &eks[(1029 + df) * 64];
                        const int t2 = myt - 1;
                        float sacc = 0.f;
                        for (int d = 0; d < 64; ++d)
                            sacc += (float)Qs[t2 * 64 + (((d >> 3) ^ (t2 & 7)) << 3) + (d & 7)] * ekp[d];
                        S[ct][r] += sacc;
                    }
                }
        }

        #pragma unroll
        for (int ct = 0; ct < 4; ++ct) {
            f16x4 pk_;
            #pragma unroll
            for (int r = 0; r < 4; ++r) {
                float p = exp2f(S[ct][r]);
                Ssum += p;
                pk_[r] = (f16)p;
            }
            int colh = (((2 * ct + (quad >> 1)) ^ (myt & 7)) << 3) + (quad & 1) * 4;
            *(f16x4*)&Ps[myt * 64 + colh] = pk_;
        }
        // no barrier: Ps rows 16w..16w+15 written & read by wave w only.

        #pragma unroll
        for (int ks = 0; ks < 2; ++ks) {
            f16x8 aa = *(const f16x8*)&Ps[(16 * w + l15) * 64 + (((ks * 4 + quad) ^ (l15 & 7)) << 3)];
            #pragma unroll
            for (int ct = 0; ct < 4; ++ct) {
                f16x8 bf = *(const f16x8*)&Vs[cb][(16 * ct + l15) * 64 + (((ks * 4 + quad) ^ (l15 & 7)) << 3)];
                O[ct] = __builtin_amdgcn_mfma_f32_16x16x32_f16(aa, bf, O[ct], 0, 0, 0);
            }
        }

        const int s0g = kb * 64;
        if (s0g <= t0 + 67 && s0g + 63 >= t0 - 4) {
            #pragma unroll
            for (int r = 0; r < 4; ++r) {
                int t_loc = 16 * w + 4 * quad + r;
                int t_g = t0 + t_loc;
                int slo = max(s0g, t_g - 4), shi = min(s0g + 63, t_g + 4);
                for (int s = slo; s <= shi; ++s) {
                    int sl = s - s0g;
                    float p = (float)Ps[t_loc * 64 + (((sl >> 3) ^ (t_loc & 7)) << 3) + (sl & 7)];
                    const float* evp = &evs[(s - t_g + 4) * 64];
                    #pragma unroll
                    for (int ct = 0; ct < 4; ++ct)
                        O[ct][r] += p * evp[16 * ct + l15];
                }
            }
        }
    }

    Ssum += __shfl_xor(Ssum, 16);
    Ssum += __shfl_xor(Ssum, 32);
    if (quad == 0) ls[myt] = 1.0f / Ssum;
    __syncthreads();

    #pragma unroll
    for (int r = 0; r < 4; ++r) {
        const int t_loc = 16 * w + 4 * quad + r;
        const float rl = ls[t_loc];
        size_t rowo = ((size_t)(b * T_LEN + t0 + t_loc)) * CCH + h * DH;
        #pragma unroll
        for (int ct = 0; ct < 4; ++ct)
            ctx[rowo + 16 * ct + l15] = (f16)(O[ct][r] * rl);
    }
}

// ---------------------------------------------------------------------------
// m97-style output projection: 128(o)x128(t) tile, BK=64, single-buffer
// dma16 staging, 2 barriers/chunk. D[o][t], A=Wo f16 [o][c], B=ctx [t][c].
// grid(B*T/128, 4), block 256. fp32 out [b][o][t].
// ---------------------------------------------------------------------------
__global__ __launch_bounds__(256)
void proj_out(const f16* __restrict__ ctx, const f16* __restrict__ Wo,
              const float* __restrict__ bo, float* __restrict__ out)
{
    const int r0 = blockIdx.x * 128;   // flat (b,t)
    const int o0 = blockIdx.y * 128;
    const int tid = threadIdx.x;
    const int w = tid >> 6, lane = tid & 63;
    const int quad = lane >> 4, l15 = lane & 15;
    const int a  = w >> 1;   // o-half
    const int b2 = w & 1;    // t-half

    __shared__ __align__(16) f16 Cs[128 * 64];
    __shared__ __align__(16) f16 Wsh[128 * 64];

    const int srow = tid >> 3;
    const int scol = ((tid & 7) ^ (srow & 7)) << 3;

    const f16* Cg = ctx + (size_t)(r0 + srow) * CCH + scol;
    const f16* Wg = Wo + (size_t)(o0 + srow) * CCH + scol;

    f32x4 acc[4][4] = {};

    for (int kc = 0; kc < 8; ++kc) {
        if (kc) __syncthreads();
        const int c1 = kc * 64;
        #pragma unroll
        for (int jj = 0; jj < 4; ++jj) {
            dma16(Cg + c1 + (size_t)(32 * jj) * CCH, &Cs[((size_t)tid + 256 * jj) * 8]);
            dma16(Wg + c1 + (size_t)(32 * jj) * CCH, &Wsh[((size_t)tid + 256 * jj) * 8]);
        }
        __syncthreads();

        #pragma unroll
        for (int ks = 0; ks < 2; ++ks) {
            const int sl = ((ks * 4 + quad) ^ (l15 & 7)) << 3;
            f16x8 wf[4], cf[4];
            #pragma unroll
            for (int i = 0; i < 4; ++i)
                wf[i] = *(const f16x8*)&Wsh[(64 * a + 16 * i + l15) * 64 + sl];
            #pragma unroll
            for (int j = 0; j < 4; ++j)
                cf[j] = *(const f16x8*)&Cs[(64 * b2 + 16 * j + l15) * 64 + sl];
            #pragma unroll
            for (int i = 0; i < 4; ++i)
                #pragma unroll
                for (int j = 0; j < 4; ++j)
                    acc[i][j] = __builtin_amdgcn_mfma_f32_16x16x32_f16(
                        wf[i], cf[j], acc[i][j], 0, 0, 0);
        }
    }

    const int bb = r0 >> 10, tb = r0 & 1023;
    #pragma unroll
    for (int i = 0; i < 4; ++i) {
        float4 bv4 = *(const float4*)&bo[o0 + 64 * a + 16 * i + 4 * quad];
        float bl[4] = {bv4.x, bv4.y, bv4.z, bv4.w};
        #pragma unroll
        for (int r = 0; r < 4; ++r) {
            size_t row = ((size_t)(bb * CCH + o0 + 64 * a + 16 * i + 4 * quad + r)) * T_LEN;
            #pragma unroll
            for (int j = 0; j < 4; ++j)
                out[row + tb + 64 * b2 + 16 * j + l15] = acc[i][j][r] + bl[r];
        }
    }
}

// ---------------------------------------------------------------------------
extern "C" void kernel_launch(void* const* d_in, const int* in_sizes, int n_in,
                              void* d_out, int out_size, void* d_ws, size_t ws_size,
                              hipStream_t stream)
{
    const float* x_q = (const float*)d_in[0];
    const float* x_k = (const float*)d_in[1];
    const float* x_v = (const float*)d_in[2];
    const float* Wq  = (const float*)d_in[3];
    const float* bq  = (const float*)d_in[4];
    const float* Wk  = (const float*)d_in[5];
    const float* bk  = (const float*)d_in[6];
    const float* Wv  = (const float*)d_in[7];
    const float* bv  = (const float*)d_in[8];
    const float* Wo  = (const float*)d_in[9];
    const float* bo  = (const float*)d_in[10];
    const float* erk = (const float*)d_in[11];
    const float* erv = (const float*)d_in[12];

    const int B = in_sizes[0] / (CCH * T_LEN);
    const size_t te = (size_t)B * CCH * T_LEN;
    const size_t we = (size_t)CCH * CCH;

    f16* p = (f16*)d_ws;
    f16* xTq = p; p += te;
    f16* xTk = p; p += te;
    f16* xTv = p; p += te;
    f16* wqh = p; p += we;
    f16* wkh = p; p += we;
    f16* wvh = p; p += we;
    f16* woh = p; p += we;
    f16* qh  = p; p += te;
    f16* kh  = p; p += te;
    f16* vh  = p; p += te;
    f16* ch  = p; p += te;

    dim3 blk(256);
    prep_kernel<<<dim3(16, 8, 3 * B + 8), blk, 0, stream>>>(
        x_q, x_k, x_v, Wq, Wk, Wv, Wo, xTq, xTk, xTv, wqh, wkh, wvh, woh, B);
    proj_qkv<<<dim3(B * 8, 4, 3), blk, 0, stream>>>(
        xTq, xTk, xTv, wqh, wkh, wvh, bq, bk, bv, qh, kh, vh);
    attn_mfma<<<dim3(T_LEN / 64, NH, B), blk, 0, stream>>>(
        qh, kh, vh, erk, erv, ch);
    proj_out<<<dim3(B * 8, 4), blk, 0, stream>>>(
        ch, woh, bo, (float*)d_out);
}